// Round 22
// baseline (145.672 us; speedup 1.0000x reference)
//
#include <hip/hip_runtime.h>
#include <hip/hip_bf16.h>
#include <math.h>

#define NHEAD 12
#define MDIM 32
#define CDIM 384
#define BATCH 4
#define NTOK 3137
#define NTOKP 3200
#define NPIX 3136
#define NXDIM 56
#define WW 7
#define W2 49
#define NKEYP 448
#define NT 28
#define NEGV -1000000000.0f
#define QSCALE 0.17677669529663687f
#define LOG2E 1.4426950408889634f
#define QS2 (0.17677669529663687f * 1.4426950408889634f)
#define NROWS 12548
#define NROWP 12800
#define GCH 8
#define GCHSZ 393

typedef unsigned int u32;
typedef unsigned short u16;
typedef __attribute__((ext_vector_type(8))) short bf16x8;
typedef __attribute__((ext_vector_type(4))) float f32x4;

__device__ __forceinline__ u32 pk_bf16(float a, float b){
  u16 x = __builtin_bit_cast(u16, __float2bfloat16(a));
  u16 y = __builtin_bit_cast(u16, __float2bfloat16(b));
  return (u32)x | ((u32)y << 16);
}
__device__ __forceinline__ u16 to_bf(float a){
  return __builtin_bit_cast(u16, __float2bfloat16(a));
}
__device__ __forceinline__ float bf_lo(u32 u){ return __uint_as_float(u << 16); }
__device__ __forceinline__ float bf_hi(u32 u){ return __uint_as_float(u & 0xffff0000u); }
__device__ __forceinline__ float ex2(float x){ return __builtin_amdgcn_exp2f(x); }

__device__ __forceinline__ int key_tok(int key, int mi, int nj, bool& valid){
  if (key == 0) { valid = true; return 0; }
  if (key > 441) { valid = false; return 0; }
  int j = key - 1, kk = j / 49, t = j - kk * 49;
  int px = mi + kk / 3 - 1, py = nj + kk % 3 - 1;
  valid = (px >= 0) && (px < 8) && (py >= 0) && (py < 8);
  return valid ? (1 + (px * WW + t / WW) * NXDIM + (py * WW + t % WW)) : 0;
}

// ---------------- P: ALL prep work in one dispatch ----------------
__global__ __launch_bounds__(256) void k_prep_all(
    const float* __restrict__ x, u16* __restrict__ xb,
    const float* __restrict__ wq, const float* __restrict__ wkv,
    const float* __restrict__ wkvg, u16* __restrict__ Wt,
    const float* __restrict__ wproj, u16* __restrict__ wph,
    int* __restrict__ ktokA, int* __restrict__ ktokL,
    const float* __restrict__ lbt, const float* __restrict__ g2l,
    const int* __restrict__ rel, float* __restrict__ bias_pk,
    const float* __restrict__ wqg, float* __restrict__ qgw,
    u32* __restrict__ tmask, u16* __restrict__ msk16)
{
  __shared__ float t[64][65];
  int tid = threadIdx.x;
  int id = blockIdx.x;
  if (id < 2400) {
    int idx = id * 256 + tid;
    int r = idx / 48, o8 = (idx % 48) * 8;
    int b = r / NTOKP, n = r - b * NTOKP;
    uint4 o = make_uint4(0, 0, 0, 0);
    if (n < NTOK) {
      const float* xp = x + ((size_t)(b * NTOK + n) * CDIM + o8);
      float4 a0 = *(const float4*)xp;
      float4 a1 = *(const float4*)(xp + 4);
      o.x = pk_bf16(a0.x, a0.y); o.y = pk_bf16(a0.z, a0.w);
      o.z = pk_bf16(a1.x, a1.y); o.w = pk_bf16(a1.z, a1.w);
    }
    *(uint4*)(xb + (size_t)r * CDIM + o8) = o;
  } else if (id < 2580) {
    int i = id - 2400;
    int n0 = (i % 30) * 64, k0 = (i / 30) * 64;
    const float* Wp; int ld, coff;
    if (n0 < 384)       { Wp = wq;   ld = 384; coff = n0; }
    else if (n0 < 1152) { Wp = wkv;  ld = 768; coff = n0 - 384; }
    else                { Wp = wkvg; ld = 768; coff = n0 - 1152; }
    int nx = (tid & 15) * 4, ky = tid >> 4;
#pragma unroll
    for (int p = 0; p < 4; ++p) {
      int k = ky + p * 16;
      float4 v = *(const float4*)(Wp + (size_t)(k0 + k) * ld + coff + nx);
      t[nx + 0][k] = v.x; t[nx + 1][k] = v.y; t[nx + 2][k] = v.z; t[nx + 3][k] = v.w;
    }
    __syncthreads();
    int row = tid >> 3, seg = tid & 7;
#pragma unroll
    for (int p = 0; p < 2; ++p) {
      int n = row + p * 32;
      const float* src = &t[n][seg * 8];
      uint4 o;
      o.x = pk_bf16(src[0], src[1]); o.y = pk_bf16(src[2], src[3]);
      o.z = pk_bf16(src[4], src[5]); o.w = pk_bf16(src[6], src[7]);
      *(uint4*)(Wt + (size_t)(n0 + n) * CDIM + k0 + seg * 8) = o;
    }
  } else if (id < 2616) {
    int i = id - 2580;
    int c0 = (i % 6) * 64, k0 = (i / 6) * 64;
    int cx = (tid & 15) * 4, ky = tid >> 4;
#pragma unroll
    for (int p = 0; p < 4; ++p) {
      int k = ky + p * 16;
      float4 v = *(const float4*)(wproj + (size_t)(k0 + k) * CDIM + c0 + cx);
      t[cx + 0][k] = v.x; t[cx + 1][k] = v.y; t[cx + 2][k] = v.z; t[cx + 3][k] = v.w;
    }
    __syncthreads();
    int row = tid >> 3, seg = tid & 7;
#pragma unroll
    for (int p = 0; p < 2; ++p) {
      int c = row + p * 32;
      const float* src = &t[c][seg * 8];
      uint4 o;
      o.x = pk_bf16(src[0], src[1]); o.y = pk_bf16(src[2], src[3]);
      o.z = pk_bf16(src[4], src[5]); o.w = pk_bf16(src[6], src[7]);
      *(uint4*)(wph + (size_t)(c0 + c) * CDIM + k0 + seg * 8) = o;
    }
  } else if (id < 2728) {
    int idx = (id - 2616) * 256 + tid;
    int wid = idx / NKEYP, key = idx - wid * NKEYP;
    int mi = wid >> 3, nj = wid & 7;
    bool valid; int n = key_tok(key, mi, nj, valid);
    int tok = valid ? n : 0;
    ktokL[idx] = tok;
    int tt = key >> 4, r = key & 15;
    ktokA[wid * NKEYP + r * NT + tt] = tok;
  } else if (id < 3064) {
    int idx = (id - 2728) * 256 + tid;
    int lane = idx & 63;
    int tt = (idx >> 6) % NT;
    int hw = (idx >> 6) / NT;
    int w = hw & 3, h = hw >> 2;
    int g = lane >> 4;
    int q = 16 * w + (lane & 15); if (q > 48) q = 48;
    float4 v;
    float* vp = (float*)&v;
#pragma unroll
    for (int r = 0; r < 4; ++r) {
      int k = 16 * tt + 4 * g + r;
      float val;
      if (k == 0) val = g2l[NHEAD + h];
      else if (k <= 441) val = lbt[rel[q * 441 + (k - 1)] * NHEAD + h];
      else val = NEGV;
      vp[r] = val * LOG2E;   // log2 domain
    }
    *(float4*)(bias_pk + (size_t)idx * 4) = v;
  } else if (id < 3068) {
    int b = id - 3064;
    float* xr = &t[0][0];
    for (int c2 = tid; c2 < CDIM; c2 += 256) xr[c2] = x[(size_t)b * NTOK * CDIM + c2];
    __syncthreads();
    for (int c2 = tid; c2 < CDIM; c2 += 256) {
      float acc = 0.f;
      for (int kk = 0; kk < CDIM; ++kk) acc += xr[kk] * wqg[(size_t)kk * CDIM + c2];
      qgw[(size_t)b * CDIM + c2] = acc * QS2;   // log2 domain
    }
  } else {
    if (tid < 64) {
      int wid = tid, mi = wid >> 3, nj = wid & 7;
      u32 msk = 0;
      for (int tt = 0; tt < NT; ++tt) {
        u32 bits = 0;
        for (int r = 0; r < 16; ++r) {
          int k = 16 * tt + r;
          if (k < 442) { bool v; key_tok(k, mi, nj, v); if (v) bits |= (1u << r); }
        }
        msk16[wid * NT + tt] = (u16)bits;
        if (bits) msk |= (1u << tt);
      }
      tmask[wid] = msk;
    }
  }
}

// ---------------- K1: qkv projection, branchless head-major epilogue ----------------
__global__ __launch_bounds__(256) void k_qkv_mfma(
    const u16* __restrict__ xb, const u16* __restrict__ Wt,
    u16* __restrict__ qb, u16* __restrict__ kb, u16* __restrict__ vb,
    u16* __restrict__ kgb, u16* __restrict__ vgb)
{
  __shared__ __align__(16) u16 As[128][72];
  __shared__ __align__(16) u16 Bs[128][72];
  int tid = threadIdx.x, lane = tid & 63, wv = tid >> 6;
  int r16 = lane & 15, g = lane >> 4;
  int orig = blockIdx.x;
  int xcd = orig & 7, idx = orig >> 3;
  int wgid = (xcd < 4 ? xcd * 188 : 752 + (xcd - 4) * 187) + idx;
  int by = wgid % 15, bx = wgid / 15;
  int tok0 = bx * 128, n0 = by * 128;
  int wm = wv >> 1, wn = wv & 1;
  int srow = tid >> 3, sseg = tid & 7;
  f32x4 acc[4][4] = {};
  for (int k0 = 0; k0 < CDIM; k0 += 64) {
    __syncthreads();
#pragma unroll
    for (int p = 0; p < 4; ++p) {
      int row = srow + p * 32;
      uint4 a = *(const uint4*)(xb + (size_t)(tok0 + row) * CDIM + k0 + sseg * 8);
      *(uint4*)&As[row][sseg * 8] = a;
      uint4 b = *(const uint4*)(Wt + (size_t)(n0 + row) * CDIM + k0 + sseg * 8);
      *(uint4*)&Bs[row][sseg * 8] = b;
    }
    __syncthreads();
#pragma unroll
    for (int ks = 0; ks < 2; ++ks) {
      bf16x8 af[4], bfr[4];
#pragma unroll
      for (int i = 0; i < 4; ++i) {
        af[i]  = *(const bf16x8*)&As[wm * 64 + i * 16 + r16][ks * 32 + g * 8];
        bfr[i] = *(const bf16x8*)&Bs[wn * 64 + i * 16 + r16][ks * 32 + g * 8];
      }
#pragma unroll
      for (int i = 0; i < 4; ++i)
#pragma unroll
        for (int j = 0; j < 4; ++j)
          acc[i][j] = __builtin_amdgcn_mfma_f32_16x16x32_bf16(af[i], bfr[j], acc[i][j], 0, 0, 0);
    }
  }
  int b = tok0 / NTOKP;
  int nb = tok0 - b * NTOKP;
#pragma unroll
  for (int j = 0; j < 4; ++j) {
    int chan0 = n0 + wn * 64 + j * 16;
    int region = chan0 / 384;
    int cm = chan0 - region * 384;
    int h = cm >> 5, dbase = cm & 16;
    u16* buf = (region == 0) ? qb : (region == 1) ? kb : (region == 2) ? vb
             : (region == 3) ? kgb : vgb;
    float scale = (region == 0) ? (float)QS2 : 1.0f;
    u16* dst = buf + ((size_t)(b * NHEAD + h) * NTOKP) * MDIM + dbase + r16;
#pragma unroll
    for (int i = 0; i < 4; ++i) {
      int nr = nb + wm * 64 + i * 16 + 4 * g;
      f32x4 v = acc[i][j];
#pragma unroll
      for (int r = 0; r < 4; ++r)
        dst[(size_t)(nr + r) * MDIM] = to_bf(v[r] * scale);
    }
  }
}

// ---------------- K2: local attention (ids 0..3071) + glob partials (ids 3072..3455) ----------------
__global__ __launch_bounds__(256, 5) void k_local(
    const u16* __restrict__ qb, const u16* __restrict__ kb, const u16* __restrict__ vb,
    const float* __restrict__ bias_pk, const int* __restrict__ ktokA,
    const int* __restrict__ ktokL, const u32* __restrict__ tmask,
    const u16* __restrict__ msk16,
    u16* __restrict__ x1b,
    const float* __restrict__ qgw, const u16* __restrict__ kgb,
    const u16* __restrict__ vgb, const float* __restrict__ g2l,
    const float* __restrict__ g2g, float* __restrict__ gpart)
{
  __shared__ __align__(16) u16 Vt[32][456];

  int tid = threadIdx.x, lane = tid & 63, wv = tid >> 6;
  int id = blockIdx.x;
  if (id < 3072) {
    int r16 = lane & 15, g = lane >> 4;
    int wlin = (id & 7) * 384 + (id >> 3);
    int bh = wlin >> 6, wid = wlin & 63;
    int b = bh / NHEAD, h = bh - b * NHEAD;
    int mi = wid >> 3, nj = wid & 7;
    const u16* kbh = kb + (size_t)bh * NTOKP * MDIM;
    const u16* vbh = vb + (size_t)bh * NTOKP * MDIM;
    const u16* qbh = qb + (size_t)bh * NTOKP * MDIM;
    const int* tA = ktokA + wid * NKEYP;
    const int* tL = ktokL + wid * NKEYP;
    const u16* mw16 = msk16 + wid * NT;
    u32 tm = tmask[wid];

    {
      int l15 = lane & 15, lg = lane >> 4;
#pragma unroll
      for (int u = wv; u < 28; u += 4) {
        int dq = u & 1, it = u >> 1;
        int kp = it * 16 + l15;
        int d0 = dq * 16 + lg * 4;
        int key0 = 2 * kp;
        int t0_ = tL[key0], t1_ = tL[key0 + 1];
        uint2 a0 = *(const uint2*)(vbh + (size_t)t0_ * MDIM + d0);
        uint2 a1 = *(const uint2*)(vbh + (size_t)t1_ * MDIM + d0);
        int w = key0 & 31;
        int col = (key0 & ~31) | (((w >> 2) & 3) << 3) | ((w >> 4) << 2) | (w & 3);
        *(u32*)&Vt[d0 + 0][col] = (a0.x & 0xffffu) | (a1.x << 16);
        *(u32*)&Vt[d0 + 1][col] = (a0.x >> 16)     | (a1.x & 0xffff0000u);
        *(u32*)&Vt[d0 + 2][col] = (a0.y & 0xffffu) | (a1.y << 16);
        *(u32*)&Vt[d0 + 3][col] = (a0.y >> 16)     | (a1.y & 0xffff0000u);
      }
    }

    int q0 = wv * 16 + r16, qc = (q0 < W2) ? q0 : 48;
    int qpix = (mi * WW + qc / WW) * NXDIM + (nj * WW + qc % WW);
    uint4 qv = *(const uint4*)(qbh + (size_t)(1 + qpix) * MDIM + 8 * g);
    bf16x8 qf = __builtin_bit_cast(bf16x8, qv);

    int4 ta[7];
#pragma unroll
    for (int i = 0; i < 7; ++i) ta[i] = *(const int4*)(tA + r16 * NT + 4 * i);

    __syncthreads();

    const float* bp = bias_pk + (size_t)(h * 4 + wv) * NT * 256 + lane * 4;
    f32x4 o0a = {0.f,0.f,0.f,0.f}, o0b = {0.f,0.f,0.f,0.f};
    f32x4 o1a = {0.f,0.f,0.f,0.f}, o1b = {0.f,0.f,0.f,0.f};
    float ssum = 0.f;

    // 2-deep K prefetch ring (static indices under full unroll); bias 1-deep
    uint4 kAs[2], kBs[2]; float4 bA, bB;
    {
      int4 tv = ta[0];
      kAs[0] = *(const uint4*)(kbh + (size_t)tv.x * MDIM + 8 * g);
      kBs[0] = *(const uint4*)(kbh + (size_t)tv.y * MDIM + 8 * g);
      kAs[1] = *(const uint4*)(kbh + (size_t)tv.z * MDIM + 8 * g);
      kBs[1] = *(const uint4*)(kbh + (size_t)tv.w * MDIM + 8 * g);
      bA = *(const float4*)(bp);
      bB = *(const float4*)(bp + 256);
    }
#pragma unroll
    for (int c = 0; c < 14; ++c) {
      float4 nbA, nbB;
      if (c < 13) {
        int t0n = 2 * (c + 1);
        nbA = *(const float4*)(bp + t0n * 256);
        nbB = *(const float4*)(bp + (t0n + 1) * 256);
      }
      if (((tm >> (2 * c)) & 3u) != 0u) {
        u32 mb0 = mw16[2 * c], mb1 = mw16[2 * c + 1];
        u32 nib0 = (mb0 >> (4 * g)) & 0xFu;
        u32 nib1 = (mb1 >> (4 * g)) & 0xFu;
        f32x4 c0 = {bA.x, bA.y, bA.z, bA.w};
        f32x4 c1 = {bB.x, bB.y, bB.z, bB.w};
        f32x4 a0 = __builtin_amdgcn_mfma_f32_16x16x32_bf16(
            __builtin_bit_cast(bf16x8, kAs[c & 1]), qf, c0, 0, 0, 0);
        f32x4 a1 = __builtin_amdgcn_mfma_f32_16x16x32_bf16(
            __builtin_bit_cast(bf16x8, kBs[c & 1]), qf, c1, 0, 0, 0);
        f32x4 e0, e1;
        e0.x = ex2(a0.x) * (float)(nib0 & 1u);
        e0.y = ex2(a0.y) * (float)((nib0 >> 1) & 1u);
        e0.z = ex2(a0.z) * (float)((nib0 >> 2) & 1u);
        e0.w = ex2(a0.w) * (float)((nib0 >> 3) & 1u);
        e1.x = ex2(a1.x) * (float)(nib1 & 1u);
        e1.y = ex2(a1.y) * (float)((nib1 >> 1) & 1u);
        e1.z = ex2(a1.z) * (float)((nib1 >> 2) & 1u);
        e1.w = ex2(a1.w) * (float)((nib1 >> 3) & 1u);
        ssum += ((e0.x + e0.y) + (e0.z + e0.w)) + ((e1.x + e1.y) + (e1.z + e1.w));
        uint4 pv;
        pv.x = pk_bf16(e0.x, e0.y); pv.y = pk_bf16(e0.z, e0.w);
        pv.z = pk_bf16(e1.x, e1.y); pv.w = pk_bf16(e1.z, e1.w);
        uint4 v0 = *(const uint4*)&Vt[r16][32 * c + 8 * g];
        uint4 v1 = *(const uint4*)&Vt[16 + r16][32 * c + 8 * g];
        if (c & 1) {
          o0b = __builtin_amdgcn_mfma_f32_16x16x32_bf16(
              __builtin_bit_cast(bf16x8, v0), __builtin_bit_cast(bf16x8, pv), o0b, 0, 0, 0);
          o1b = __builtin_amdgcn_mfma_f32_16x16x32_bf16(
              __builtin_bit_cast(bf16x8, v1), __builtin_bit_cast(bf16x8, pv), o1b, 0, 0, 0);
        } else {
          o0a = __builtin_amdgcn_mfma_f32_16x16x32_bf16(
              __builtin_bit_cast(bf16x8, v0), __builtin_bit_cast(bf16x8, pv), o0a, 0, 0, 0);
          o1a = __builtin_amdgcn_mfma_f32_16x16x32_bf16(
              __builtin_bit_cast(bf16x8, v1), __builtin_bit_cast(bf16x8, pv), o1a, 0, 0, 0);
        }
      }
      if (c < 12) {
        // load chunk c+2 into the slot just consumed (same parity)
        int cn = c + 2;
        int4 tv = ta[cn >> 1];
        int tn0 = (cn & 1) ? tv.z : tv.x;
        int tn1 = (cn & 1) ? tv.w : tv.y;
        kAs[c & 1] = *(const uint4*)(kbh + (size_t)tn0 * MDIM + 8 * g);
        kBs[c & 1] = *(const uint4*)(kbh + (size_t)tn1 * MDIM + 8 * g);
      }
      if (c < 13) { bA = nbA; bB = nbB; }
    }
    f32x4 o0 = o0a + o0b, o1 = o1a + o1b;
    ssum += __shfl_xor(ssum, 16);
    ssum += __shfl_xor(ssum, 32);

    if (q0 < W2) {
      float inv = 1.f / ssum;
      size_t base = ((size_t)b * NPIX + qpix) * CDIM + h * MDIM;
      uint2 hw0 = make_uint2(pk_bf16(o0.x * inv, o0.y * inv), pk_bf16(o0.z * inv, o0.w * inv));
      uint2 hw1 = make_uint2(pk_bf16(o1.x * inv, o1.y * inv), pk_bf16(o1.z * inv, o1.w * inv));
      *(uint2*)&x1b[base + 4 * g]      = hw0;
      *(uint2*)&x1b[base + 16 + 4 * g] = hw1;
    }
  } else {
    int gi = id - 3072;
    int ch = gi & 7, bh = gi >> 3;
    int b = bh / NHEAD, h = bh - b * NHEAD;
    int n0c = ch * GCHSZ, n1c = min(NTOK, n0c + GCHSZ);
    float* sh = (float*)&Vt[0][0];
    float* qg = sh;
    float* lg = sh + 32;
    float* red = sh + 432;
    float* accw = sh + 436;
    float* sw = sh + 564;
    int tid2 = tid, wv2 = tid >> 6;
    if (tid2 < 32) qg[tid2] = qgw[(size_t)b * CDIM + h * MDIM + tid2];
    __syncthreads();
    const u16* kbh = kgb + (size_t)bh * NTOKP * MDIM;
    const u16* vbh = vgb + (size_t)bh * NTOKP * MDIM;
    float b0 = LOG2E * g2g[h], b1 = LOG2E * g2l[h];
    float lmax = -INFINITY;
    for (int n = n0c + tid2; n < n1c; n += 256) {
      const uint4* kr = (const uint4*)(kbh + (size_t)n * MDIM);
      float dot = 0.f;
#pragma unroll
      for (int gg = 0; gg < 4; ++gg) {
        uint4 u = kr[gg];
        dot += qg[8*gg+0]*bf_lo(u.x) + qg[8*gg+1]*bf_hi(u.x);
        dot += qg[8*gg+2]*bf_lo(u.y) + qg[8*gg+3]*bf_hi(u.y);
        dot += qg[8*gg+4]*bf_lo(u.z) + qg[8*gg+5]*bf_hi(u.z);
        dot += qg[8*gg+6]*bf_lo(u.w) + qg[8*gg+7]*bf_hi(u.w);
      }
      dot += (n == 0) ? b0 : b1;
      lg[n - n0c] = dot;
      lmax = fmaxf(lmax, dot);
    }
#pragma unroll
    for (int off = 32; off; off >>= 1) lmax = fmaxf(lmax, __shfl_down(lmax, off));
    if ((tid2 & 63) == 0) red[wv2] = lmax;
    __syncthreads();
    float M = fmaxf(fmaxf(red[0], red[1]), fmaxf(red[2], red[3]));
    float s = 0.f, acc[32] = {};
    for (int n = n0c + tid2; n < n1c; n += 256) {
      float p = ex2(lg[n - n0c] - M);
      s += p;
      const uint4* vr = (const uint4*)(vbh + (size_t)n * MDIM);
#pragma unroll
      for (int gg = 0; gg < 4; ++gg) {
        uint4 u = vr[gg];
        acc[8*gg+0] += p * bf_lo(u.x); acc[8*gg+1] += p * bf_hi(u.x);
        acc[8*gg+2] += p * bf_lo(u.y); acc[8*gg+3] += p * bf_hi(u.y);
        acc[8*gg+4] += p * bf_lo(u.z); acc[8*gg+5] += p * bf_hi(u.z);
        acc[8*gg+6] += p * bf_lo(u.w); acc[8*gg+7] += p * bf_hi(u.w);
      }
    }
#pragma unroll
    for (int off = 32; off; off >>= 1) {
      s += __shfl_down(s, off);
#pragma unroll
      for (int d = 0; d < 32; ++d) acc[d] += __shfl_down(acc[d], off);
    }
    if ((tid2 & 63) == 0) {
      sw[wv2] = s;
#pragma unroll
      for (int d = 0; d < 32; ++d) accw[wv2 * 32 + d] = acc[d];
    }
    __syncthreads();
    if (tid2 < 32) {
      float S = sw[0] + sw[1] + sw[2] + sw[3];
      float o = accw[tid2] + accw[32 + tid2] + accw[64 + tid2] + accw[96 + tid2];
      float* pp = gpart + ((size_t)bh * GCH + ch) * 36;
      if (tid2 == 0) { pp[0] = M; pp[1] = S; }
      pp[2 + tid2] = o;
    }
  }
}

// ---------------- K4: x1 projection (0..293) + parallel glob finalize (294..297) ----------------
__global__ __launch_bounds__(256, 4) void k_proj_mfma(
    const u16* __restrict__ x1b, const u16* __restrict__ wph,
    const float* __restrict__ bproj, float* __restrict__ out,
    const float* __restrict__ gpart, const float* __restrict__ wprojg,
    const float* __restrict__ bprojg)
{
  __shared__ __align__(16) u16 Ab[128][72];   // x1 rows (tokens)
  __shared__ __align__(16) u16 Bb[128][72];   // wproj rows (out cols)
  int tid = threadIdx.x;
  int id = blockIdx.x;
  if (id >= 294) {
    // glob finalize: one block per batch element
    int b = id - 294;
    float* x0s = (float*)&Ab[0][0];   // 384 floats
    for (int it = tid; it < NHEAD * 32; it += 256) {
      int h = it >> 5, d = it & 31;
      const float* pp = gpart + (size_t)(b * NHEAD + h) * GCH * 36;
      float M = -INFINITY;
#pragma unroll
      for (int c = 0; c < GCH; ++c) M = fmaxf(M, pp[c * 36]);
      float S = 0.f, o = 0.f;
#pragma unroll
      for (int c = 0; c < GCH; ++c) {
        float f = ex2(pp[c * 36] - M);
        S += pp[c * 36 + 1] * f;
        o += pp[c * 36 + 2 + d] * f;
      }
      x0s[h * 32 + d] = o / S;
    }
    __syncthreads();
    for (int c = tid; c < CDIM; c += 256) {
      float acc = bprojg[c];
      for (int kk = 0; kk < CDIM; ++kk) acc += x0s[kk] * wprojg[(size_t)kk * CDIM + c];
      out[(size_t)b * NTOK * CDIM + c] = acc;
    }
    return;
  }
  int lane = tid & 63, wv = tid >> 6;
  int r16 = lane & 15, g = lane >> 4;
  const int q8 = 36, r8 = 6;
  int xcd = id & 7, idx = id >> 3;
  int wgid = (xcd < r8 ? xcd * (q8 + 1) : r8 * (q8 + 1) + (xcd - r8) * q8) + idx;
  int by = wgid % 3, bx = wgid / 3;
  int row0 = bx * 128, n0 = by * 128;
  int wc = wv >> 1, wtk = wv & 1;
  int srow = tid >> 3, sseg = tid & 7;
  f32x4 acc[4][4] = {};                       // [col frag][row frag]
  for (int k0 = 0; k0 < CDIM; k0 += 64) {
    __syncthreads();
#pragma unroll
    for (int p = 0; p < 4; ++p) {
      int row = srow + p * 32;
      *(uint4*)&Ab[row][sseg * 8] = *(const uint4*)(x1b + (size_t)(row0 + row) * CDIM + k0 + sseg * 8);
      *(uint4*)&Bb[row][sseg * 8] = *(const uint4*)(wph + (size_t)(n0 + row) * CDIM + k0 + sseg * 8);
    }
    __syncthreads();
#pragma unroll
    for (int ks = 0; ks < 2; ++ks) {
      bf16x8 cf[4], rf[4];
#pragma unroll
      for (int i = 0; i < 4; ++i) {
        cf[i] = *(const bf16x8*)&Bb[wc * 64 + i * 16 + r16][ks * 32 + g * 8];
        rf[i] = *(const bf16x8*)&Ab[wtk * 64 + i * 16 + r16][ks * 32 + g * 8];
      }
#pragma unroll
      for (int i = 0; i < 4; ++i)
#pragma unroll
        for (int j = 0; j < 4; ++j)
          acc[i][j] = __builtin_amdgcn_mfma_f32_16x16x32_bf16(cf[i], rf[j], acc[i][j], 0, 0, 0);
    }
  }
#pragma unroll
  for (int i = 0; i < 4; ++i) {
    int col = n0 + wc * 64 + i * 16 + 4 * g;
    float4 bpv = *(const float4*)(bproj + col);
#pragma unroll
    for (int j = 0; j < 4; ++j) {
      int rr = row0 + wtk * 64 + j * 16 + r16;
      int b = (rr >= NPIX) + (rr >= 2 * NPIX) + (rr >= 3 * NPIX);
      int p = rr - b * NPIX;
      f32x4 v = acc[i][j];
      float4 o = make_float4(v.x + bpv.x, v.y + bpv.y, v.z + bpv.z, v.w + bpv.w);
      *(float4*)&out[((size_t)b * NTOK + 1 + p) * CDIM + col] = o;
    }
  }
}

extern "C" void kernel_launch(void* const* d_in, const int* in_sizes, int n_in,
                              void* d_out, int out_size, void* d_ws, size_t ws_size,
                              hipStream_t stream)
{
  const float* x      = (const float*)d_in[0];
  const float* wq     = (const float*)d_in[1];
  const float* wkv    = (const float*)d_in[2];
  const float* wproj  = (const float*)d_in[3];
  const float* bproj  = (const float*)d_in[4];
  const float* wqg    = (const float*)d_in[5];
  const float* wkvg   = (const float*)d_in[6];
  const float* wprojg = (const float*)d_in[7];
  const float* bprojg = (const float*)d_in[8];
  const float* lbt    = (const float*)d_in[9];
  const float* g2l    = (const float*)d_in[10];
  const float* g2g    = (const float*)d_in[11];
  const int*   rel    = (const int*)d_in[12];
  float* out = (float*)d_out;

  char* wsb = (char*)d_ws;
  const size_t hbsz = (size_t)BATCH * NHEAD * NTOKP * MDIM * 2;
  u16* qb  = (u16*)wsb;     wsb += hbsz;
  u16* kb  = (u16*)wsb;     wsb += hbsz;
  u16* vb  = (u16*)wsb;     wsb += hbsz;
  u16* kgb = (u16*)wsb;     wsb += hbsz;
  u16* vgb = (u16*)wsb;     wsb += hbsz;
  u16* x1b = (u16*)wsb;     wsb += (size_t)BATCH * NPIX * CDIM * 2;
  float* bias_pk = (float*)wsb; wsb += (size_t)NHEAD * 4 * NT * 64 * 4 * 4;
  u16* xb = (u16*)wsb;      wsb += (size_t)NROWP * CDIM * 2;
  u16* Wt = (u16*)wsb;      wsb += (size_t)1920 * CDIM * 2;
  u16* wph = (u16*)wsb;     wsb += (size_t)CDIM * CDIM * 2;
  int* ktokA = (int*)wsb;   wsb += (size_t)64 * NKEYP * 4;
  int* ktokL = (int*)wsb;   wsb += (size_t)64 * NKEYP * 4;
  float* qgw = (float*)wsb; wsb += (size_t)BATCH * CDIM * 4;
  float* gpart = (float*)wsb; wsb += (size_t)BATCH * NHEAD * GCH * 36 * 4;
  u32* tmask = (u32*)wsb;   wsb += (size_t)64 * 4;
  u16* msk16 = (u16*)wsb;   wsb += (size_t)64 * NT * 2;

  k_prep_all<<<3069, 256, 0, stream>>>(x, xb, wq, wkv, wkvg, Wt, wproj, wph,
                                       ktokA, ktokL, lbt, g2l, rel, bias_pk,
                                       wqg, qgw, tmask, msk16);

  k_qkv_mfma<<<1500, 256, 0, stream>>>(xb, Wt, qb, kb, vb, kgb, vgb);

  k_local<<<3456, 256, 0, stream>>>(qb, kb, vb, bias_pk, ktokA, ktokL, tmask, msk16,
                                    x1b, qgw, kgb, vgb, g2l, g2g, gpart);

  k_proj_mfma<<<298, 256, 0, stream>>>(x1b, wph, bproj, out,
                                       gpart, wprojg, bprojg);
}

// Round 23
// 145.361 us; speedup vs baseline: 1.0021x; 1.0021x over previous
//
#include <hip/hip_runtime.h>
#include <hip/hip_bf16.h>
#include <math.h>

#define NHEAD 12
#define MDIM 32
#define CDIM 384
#define BATCH 4
#define NTOK 3137
#define NTOKP 3200
#define NPIX 3136
#define NXDIM 56
#define WW 7
#define W2 49
#define NKEYP 448
#define NT 28
#define NEGV -1000000000.0f
#define QSCALE 0.17677669529663687f
#define LOG2E 1.4426950408889634f
#define QS2 (0.17677669529663687f * 1.4426950408889634f)
#define NROWS 12548
#define NROWP 12800
#define GCH 8
#define GCHSZ 393

typedef unsigned int u32;
typedef unsigned short u16;
typedef __attribute__((ext_vector_type(8))) short bf16x8;
typedef __attribute__((ext_vector_type(4))) float f32x4;

__device__ __forceinline__ u32 pk_bf16(float a, float b){
  u16 x = __builtin_bit_cast(u16, __float2bfloat16(a));
  u16 y = __builtin_bit_cast(u16, __float2bfloat16(b));
  return (u32)x | ((u32)y << 16);
}
__device__ __forceinline__ u16 to_bf(float a){
  return __builtin_bit_cast(u16, __float2bfloat16(a));
}
__device__ __forceinline__ float bf_lo(u32 u){ return __uint_as_float(u << 16); }
__device__ __forceinline__ float bf_hi(u32 u){ return __uint_as_float(u & 0xffff0000u); }
__device__ __forceinline__ float ex2(float x){ return __builtin_amdgcn_exp2f(x); }

__device__ __forceinline__ int key_tok(int key, int mi, int nj, bool& valid){
  if (key == 0) { valid = true; return 0; }
  if (key > 441) { valid = false; return 0; }
  int j = key - 1, kk = j / 49, t = j - kk * 49;
  int px = mi + kk / 3 - 1, py = nj + kk % 3 - 1;
  valid = (px >= 0) && (px < 8) && (py >= 0) && (py < 8);
  return valid ? (1 + (px * WW + t / WW) * NXDIM + (py * WW + t % WW)) : 0;
}

// ---------------- P: ALL prep work in one dispatch ----------------
__global__ __launch_bounds__(256) void k_prep_all(
    const float* __restrict__ x, u16* __restrict__ xb,
    const float* __restrict__ wq, const float* __restrict__ wkv,
    const float* __restrict__ wkvg, u16* __restrict__ Wt,
    const float* __restrict__ wproj, u16* __restrict__ wph,
    int* __restrict__ ktokA, int* __restrict__ ktokL,
    const float* __restrict__ lbt, const float* __restrict__ g2l,
    const int* __restrict__ rel, float* __restrict__ bias_pk,
    const float* __restrict__ wqg, float* __restrict__ qgw,
    u32* __restrict__ tmask, u16* __restrict__ msk16)
{
  __shared__ float t[64][65];
  int tid = threadIdx.x;
  int id = blockIdx.x;
  if (id < 2400) {
    int idx = id * 256 + tid;
    int r = idx / 48, o8 = (idx % 48) * 8;
    int b = r / NTOKP, n = r - b * NTOKP;
    uint4 o = make_uint4(0, 0, 0, 0);
    if (n < NTOK) {
      const float* xp = x + ((size_t)(b * NTOK + n) * CDIM + o8);
      float4 a0 = *(const float4*)xp;
      float4 a1 = *(const float4*)(xp + 4);
      o.x = pk_bf16(a0.x, a0.y); o.y = pk_bf16(a0.z, a0.w);
      o.z = pk_bf16(a1.x, a1.y); o.w = pk_bf16(a1.z, a1.w);
    }
    *(uint4*)(xb + (size_t)r * CDIM + o8) = o;
  } else if (id < 2580) {
    int i = id - 2400;
    int n0 = (i % 30) * 64, k0 = (i / 30) * 64;
    const float* Wp; int ld, coff;
    if (n0 < 384)       { Wp = wq;   ld = 384; coff = n0; }
    else if (n0 < 1152) { Wp = wkv;  ld = 768; coff = n0 - 384; }
    else                { Wp = wkvg; ld = 768; coff = n0 - 1152; }
    int nx = (tid & 15) * 4, ky = tid >> 4;
#pragma unroll
    for (int p = 0; p < 4; ++p) {
      int k = ky + p * 16;
      float4 v = *(const float4*)(Wp + (size_t)(k0 + k) * ld + coff + nx);
      t[nx + 0][k] = v.x; t[nx + 1][k] = v.y; t[nx + 2][k] = v.z; t[nx + 3][k] = v.w;
    }
    __syncthreads();
    int row = tid >> 3, seg = tid & 7;
#pragma unroll
    for (int p = 0; p < 2; ++p) {
      int n = row + p * 32;
      const float* src = &t[n][seg * 8];
      uint4 o;
      o.x = pk_bf16(src[0], src[1]); o.y = pk_bf16(src[2], src[3]);
      o.z = pk_bf16(src[4], src[5]); o.w = pk_bf16(src[6], src[7]);
      *(uint4*)(Wt + (size_t)(n0 + n) * CDIM + k0 + seg * 8) = o;
    }
  } else if (id < 2616) {
    int i = id - 2580;
    int c0 = (i % 6) * 64, k0 = (i / 6) * 64;
    int cx = (tid & 15) * 4, ky = tid >> 4;
#pragma unroll
    for (int p = 0; p < 4; ++p) {
      int k = ky + p * 16;
      float4 v = *(const float4*)(wproj + (size_t)(k0 + k) * CDIM + c0 + cx);
      t[cx + 0][k] = v.x; t[cx + 1][k] = v.y; t[cx + 2][k] = v.z; t[cx + 3][k] = v.w;
    }
    __syncthreads();
    int row = tid >> 3, seg = tid & 7;
#pragma unroll
    for (int p = 0; p < 2; ++p) {
      int c = row + p * 32;
      const float* src = &t[c][seg * 8];
      uint4 o;
      o.x = pk_bf16(src[0], src[1]); o.y = pk_bf16(src[2], src[3]);
      o.z = pk_bf16(src[4], src[5]); o.w = pk_bf16(src[6], src[7]);
      *(uint4*)(wph + (size_t)(c0 + c) * CDIM + k0 + seg * 8) = o;
    }
  } else if (id < 2728) {
    int idx = (id - 2616) * 256 + tid;
    int wid = idx / NKEYP, key = idx - wid * NKEYP;
    int mi = wid >> 3, nj = wid & 7;
    bool valid; int n = key_tok(key, mi, nj, valid);
    int tok = valid ? n : 0;
    ktokL[idx] = tok;
    int tt = key >> 4, r = key & 15;
    ktokA[wid * NKEYP + r * NT + tt] = tok;
  } else if (id < 3064) {
    int idx = (id - 2728) * 256 + tid;
    int lane = idx & 63;
    int tt = (idx >> 6) % NT;
    int hw = (idx >> 6) / NT;
    int w = hw & 3, h = hw >> 2;
    int g = lane >> 4;
    int q = 16 * w + (lane & 15); if (q > 48) q = 48;
    float4 v;
    float* vp = (float*)&v;
#pragma unroll
    for (int r = 0; r < 4; ++r) {
      int k = 16 * tt + 4 * g + r;
      float val;
      if (k == 0) val = g2l[NHEAD + h];
      else if (k <= 441) val = lbt[rel[q * 441 + (k - 1)] * NHEAD + h];
      else val = NEGV;
      vp[r] = val * LOG2E;   // log2 domain
    }
    *(float4*)(bias_pk + (size_t)idx * 4) = v;
  } else if (id < 3068) {
    int b = id - 3064;
    float* xr = &t[0][0];
    for (int c2 = tid; c2 < CDIM; c2 += 256) xr[c2] = x[(size_t)b * NTOK * CDIM + c2];
    __syncthreads();
    for (int c2 = tid; c2 < CDIM; c2 += 256) {
      float acc = 0.f;
      for (int kk = 0; kk < CDIM; ++kk) acc += xr[kk] * wqg[(size_t)kk * CDIM + c2];
      qgw[(size_t)b * CDIM + c2] = acc * QS2;   // log2 domain
    }
  } else {
    if (tid < 64) {
      int wid = tid, mi = wid >> 3, nj = wid & 7;
      u32 msk = 0;
      for (int tt = 0; tt < NT; ++tt) {
        u32 bits = 0;
        for (int r = 0; r < 16; ++r) {
          int k = 16 * tt + r;
          if (k < 442) { bool v; key_tok(k, mi, nj, v); if (v) bits |= (1u << r); }
        }
        msk16[wid * NT + tt] = (u16)bits;
        if (bits) msk |= (1u << tt);
      }
      tmask[wid] = msk;
    }
  }
}

// ---------------- K1: qkv projection, branchless head-major epilogue ----------------
__global__ __launch_bounds__(256) void k_qkv_mfma(
    const u16* __restrict__ xb, const u16* __restrict__ Wt,
    u16* __restrict__ qb, u16* __restrict__ kb, u16* __restrict__ vb,
    u16* __restrict__ kgb, u16* __restrict__ vgb)
{
  __shared__ __align__(16) u16 As[128][72];
  __shared__ __align__(16) u16 Bs[128][72];
  int tid = threadIdx.x, lane = tid & 63, wv = tid >> 6;
  int r16 = lane & 15, g = lane >> 4;
  int orig = blockIdx.x;
  int xcd = orig & 7, idx = orig >> 3;
  int wgid = (xcd < 4 ? xcd * 188 : 752 + (xcd - 4) * 187) + idx;
  int by = wgid % 15, bx = wgid / 15;
  int tok0 = bx * 128, n0 = by * 128;
  int wm = wv >> 1, wn = wv & 1;
  int srow = tid >> 3, sseg = tid & 7;
  f32x4 acc[4][4] = {};
  for (int k0 = 0; k0 < CDIM; k0 += 64) {
    __syncthreads();
#pragma unroll
    for (int p = 0; p < 4; ++p) {
      int row = srow + p * 32;
      uint4 a = *(const uint4*)(xb + (size_t)(tok0 + row) * CDIM + k0 + sseg * 8);
      *(uint4*)&As[row][sseg * 8] = a;
      uint4 b = *(const uint4*)(Wt + (size_t)(n0 + row) * CDIM + k0 + sseg * 8);
      *(uint4*)&Bs[row][sseg * 8] = b;
    }
    __syncthreads();
#pragma unroll
    for (int ks = 0; ks < 2; ++ks) {
      bf16x8 af[4], bfr[4];
#pragma unroll
      for (int i = 0; i < 4; ++i) {
        af[i]  = *(const bf16x8*)&As[wm * 64 + i * 16 + r16][ks * 32 + g * 8];
        bfr[i] = *(const bf16x8*)&Bs[wn * 64 + i * 16 + r16][ks * 32 + g * 8];
      }
#pragma unroll
      for (int i = 0; i < 4; ++i)
#pragma unroll
        for (int j = 0; j < 4; ++j)
          acc[i][j] = __builtin_amdgcn_mfma_f32_16x16x32_bf16(af[i], bfr[j], acc[i][j], 0, 0, 0);
    }
  }
  int b = tok0 / NTOKP;
  int nb = tok0 - b * NTOKP;
#pragma unroll
  for (int j = 0; j < 4; ++j) {
    int chan0 = n0 + wn * 64 + j * 16;
    int region = chan0 / 384;
    int cm = chan0 - region * 384;
    int h = cm >> 5, dbase = cm & 16;
    u16* buf = (region == 0) ? qb : (region == 1) ? kb : (region == 2) ? vb
             : (region == 3) ? kgb : vgb;
    float scale = (region == 0) ? (float)QS2 : 1.0f;
    u16* dst = buf + ((size_t)(b * NHEAD + h) * NTOKP) * MDIM + dbase + r16;
#pragma unroll
    for (int i = 0; i < 4; ++i) {
      int nr = nb + wm * 64 + i * 16 + 4 * g;
      f32x4 v = acc[i][j];
#pragma unroll
      for (int r = 0; r < 4; ++r)
        dst[(size_t)(nr + r) * MDIM] = to_bf(v[r] * scale);
    }
  }
}

// ---------------- K2: local attention (ids 0..3071) + glob partials (ids 3072..3455) ----------------
__global__ __launch_bounds__(256, 5) void k_local(
    const u16* __restrict__ qb, const u16* __restrict__ kb, const u16* __restrict__ vb,
    const float* __restrict__ bias_pk, const int* __restrict__ ktokA,
    const int* __restrict__ ktokL, const u32* __restrict__ tmask,
    const u16* __restrict__ msk16,
    u16* __restrict__ x1b,
    const float* __restrict__ qgw, const u16* __restrict__ kgb,
    const u16* __restrict__ vgb, const float* __restrict__ g2l,
    const float* __restrict__ g2g, float* __restrict__ gpart)
{
  __shared__ __align__(16) u16 Vt[32][456];

  int tid = threadIdx.x, lane = tid & 63, wv = tid >> 6;
  int id = blockIdx.x;
  if (id < 3072) {
    int r16 = lane & 15, g = lane >> 4;
    int wlin = (id & 7) * 384 + (id >> 3);
    int bh = wlin >> 6, wid = wlin & 63;
    int b = bh / NHEAD, h = bh - b * NHEAD;
    int mi = wid >> 3, nj = wid & 7;
    const u16* kbh = kb + (size_t)bh * NTOKP * MDIM;
    const u16* vbh = vb + (size_t)bh * NTOKP * MDIM;
    const u16* qbh = qb + (size_t)bh * NTOKP * MDIM;
    const int* tA = ktokA + wid * NKEYP;
    const int* tL = ktokL + wid * NKEYP;
    const u16* mw16 = msk16 + wid * NT;
    u32 tm = tmask[wid];

    {
      int l15 = lane & 15, lg = lane >> 4;
#pragma unroll
      for (int u = wv; u < 28; u += 4) {
        int dq = u & 1, it = u >> 1;
        int kp = it * 16 + l15;
        int d0 = dq * 16 + lg * 4;
        int key0 = 2 * kp;
        int t0_ = tL[key0], t1_ = tL[key0 + 1];
        uint2 a0 = *(const uint2*)(vbh + (size_t)t0_ * MDIM + d0);
        uint2 a1 = *(const uint2*)(vbh + (size_t)t1_ * MDIM + d0);
        int w = key0 & 31;
        int col = (key0 & ~31) | (((w >> 2) & 3) << 3) | ((w >> 4) << 2) | (w & 3);
        *(u32*)&Vt[d0 + 0][col] = (a0.x & 0xffffu) | (a1.x << 16);
        *(u32*)&Vt[d0 + 1][col] = (a0.x >> 16)     | (a1.x & 0xffff0000u);
        *(u32*)&Vt[d0 + 2][col] = (a0.y & 0xffffu) | (a1.y << 16);
        *(u32*)&Vt[d0 + 3][col] = (a0.y >> 16)     | (a1.y & 0xffff0000u);
      }
    }

    int q0 = wv * 16 + r16, qc = (q0 < W2) ? q0 : 48;
    int qpix = (mi * WW + qc / WW) * NXDIM + (nj * WW + qc % WW);
    uint4 qv = *(const uint4*)(qbh + (size_t)(1 + qpix) * MDIM + 8 * g);
    bf16x8 qf = __builtin_bit_cast(bf16x8, qv);

    int4 ta[7];
#pragma unroll
    for (int i = 0; i < 7; ++i) ta[i] = *(const int4*)(tA + r16 * NT + 4 * i);

    __syncthreads();

    const float* bp = bias_pk + (size_t)(h * 4 + wv) * NT * 256 + lane * 4;
    f32x4 o0a = {0.f,0.f,0.f,0.f}, o0b = {0.f,0.f,0.f,0.f};
    f32x4 o1a = {0.f,0.f,0.f,0.f}, o1b = {0.f,0.f,0.f,0.f};
    float ssum = 0.f;

    uint4 kA, kB; float4 bA, bB;
    {
      int4 tv = ta[0];
      kA = *(const uint4*)(kbh + (size_t)tv.x * MDIM + 8 * g);
      kB = *(const uint4*)(kbh + (size_t)tv.y * MDIM + 8 * g);
      bA = *(const float4*)(bp);
      bB = *(const float4*)(bp + 256);
    }
#pragma unroll
    for (int c = 0; c < 14; ++c) {
      uint4 nkA, nkB; float4 nbA, nbB;
      if (c < 13) {
        int t0n = 2 * (c + 1);
        int4 tv = ta[(c + 1) >> 1];
        int tn0 = ((c + 1) & 1) ? tv.z : tv.x;
        int tn1 = ((c + 1) & 1) ? tv.w : tv.y;
        nkA = *(const uint4*)(kbh + (size_t)tn0 * MDIM + 8 * g);
        nkB = *(const uint4*)(kbh + (size_t)tn1 * MDIM + 8 * g);
        nbA = *(const float4*)(bp + t0n * 256);
        nbB = *(const float4*)(bp + (t0n + 1) * 256);
      }
      if (((tm >> (2 * c)) & 3u) != 0u) {
        u32 mb0 = mw16[2 * c], mb1 = mw16[2 * c + 1];
        u32 nib0 = (mb0 >> (4 * g)) & 0xFu;
        u32 nib1 = (mb1 >> (4 * g)) & 0xFu;
        f32x4 c0 = {bA.x, bA.y, bA.z, bA.w};
        f32x4 c1 = {bB.x, bB.y, bB.z, bB.w};
        __builtin_amdgcn_s_setprio(1);
        f32x4 a0 = __builtin_amdgcn_mfma_f32_16x16x32_bf16(
            __builtin_bit_cast(bf16x8, kA), qf, c0, 0, 0, 0);
        f32x4 a1 = __builtin_amdgcn_mfma_f32_16x16x32_bf16(
            __builtin_bit_cast(bf16x8, kB), qf, c1, 0, 0, 0);
        __builtin_amdgcn_s_setprio(0);
        f32x4 e0, e1;
        e0.x = ex2(a0.x) * (float)(nib0 & 1u);
        e0.y = ex2(a0.y) * (float)((nib0 >> 1) & 1u);
        e0.z = ex2(a0.z) * (float)((nib0 >> 2) & 1u);
        e0.w = ex2(a0.w) * (float)((nib0 >> 3) & 1u);
        e1.x = ex2(a1.x) * (float)(nib1 & 1u);
        e1.y = ex2(a1.y) * (float)((nib1 >> 1) & 1u);
        e1.z = ex2(a1.z) * (float)((nib1 >> 2) & 1u);
        e1.w = ex2(a1.w) * (float)((nib1 >> 3) & 1u);
        ssum += ((e0.x + e0.y) + (e0.z + e0.w)) + ((e1.x + e1.y) + (e1.z + e1.w));
        uint4 pv;
        pv.x = pk_bf16(e0.x, e0.y); pv.y = pk_bf16(e0.z, e0.w);
        pv.z = pk_bf16(e1.x, e1.y); pv.w = pk_bf16(e1.z, e1.w);
        uint4 v0 = *(const uint4*)&Vt[r16][32 * c + 8 * g];
        uint4 v1 = *(const uint4*)&Vt[16 + r16][32 * c + 8 * g];
        __builtin_amdgcn_s_setprio(1);
        if (c & 1) {
          o0b = __builtin_amdgcn_mfma_f32_16x16x32_bf16(
              __builtin_bit_cast(bf16x8, v0), __builtin_bit_cast(bf16x8, pv), o0b, 0, 0, 0);
          o1b = __builtin_amdgcn_mfma_f32_16x16x32_bf16(
              __builtin_bit_cast(bf16x8, v1), __builtin_bit_cast(bf16x8, pv), o1b, 0, 0, 0);
        } else {
          o0a = __builtin_amdgcn_mfma_f32_16x16x32_bf16(
              __builtin_bit_cast(bf16x8, v0), __builtin_bit_cast(bf16x8, pv), o0a, 0, 0, 0);
          o1a = __builtin_amdgcn_mfma_f32_16x16x32_bf16(
              __builtin_bit_cast(bf16x8, v1), __builtin_bit_cast(bf16x8, pv), o1a, 0, 0, 0);
        }
        __builtin_amdgcn_s_setprio(0);
      }
      if (c < 13) { kA = nkA; kB = nkB; bA = nbA; bB = nbB; }
    }
    f32x4 o0 = o0a + o0b, o1 = o1a + o1b;
    ssum += __shfl_xor(ssum, 16);
    ssum += __shfl_xor(ssum, 32);

    if (q0 < W2) {
      float inv = 1.f / ssum;
      size_t base = ((size_t)b * NPIX + qpix) * CDIM + h * MDIM;
      uint2 hw0 = make_uint2(pk_bf16(o0.x * inv, o0.y * inv), pk_bf16(o0.z * inv, o0.w * inv));
      uint2 hw1 = make_uint2(pk_bf16(o1.x * inv, o1.y * inv), pk_bf16(o1.z * inv, o1.w * inv));
      *(uint2*)&x1b[base + 4 * g]      = hw0;
      *(uint2*)&x1b[base + 16 + 4 * g] = hw1;
    }
  } else {
    int gi = id - 3072;
    int ch = gi & 7, bh = gi >> 3;
    int b = bh / NHEAD, h = bh - b * NHEAD;
    int n0c = ch * GCHSZ, n1c = min(NTOK, n0c + GCHSZ);
    float* sh = (float*)&Vt[0][0];
    float* qg = sh;
    float* lg = sh + 32;
    float* red = sh + 432;
    float* accw = sh + 436;
    float* sw = sh + 564;
    int tid2 = tid, wv2 = tid >> 6;
    if (tid2 < 32) qg[tid2] = qgw[(size_t)b * CDIM + h * MDIM + tid2];
    __syncthreads();
    const u16* kbh = kgb + (size_t)bh * NTOKP * MDIM;
    const u16* vbh = vgb + (size_t)bh * NTOKP * MDIM;
    float b0 = LOG2E * g2g[h], b1 = LOG2E * g2l[h];
    float lmax = -INFINITY;
    for (int n = n0c + tid2; n < n1c; n += 256) {
      const uint4* kr = (const uint4*)(kbh + (size_t)n * MDIM);
      float dot = 0.f;
#pragma unroll
      for (int gg = 0; gg < 4; ++gg) {
        uint4 u = kr[gg];
        dot += qg[8*gg+0]*bf_lo(u.x) + qg[8*gg+1]*bf_hi(u.x);
        dot += qg[8*gg+2]*bf_lo(u.y) + qg[8*gg+3]*bf_hi(u.y);
        dot += qg[8*gg+4]*bf_lo(u.z) + qg[8*gg+5]*bf_hi(u.z);
        dot += qg[8*gg+6]*bf_lo(u.w) + qg[8*gg+7]*bf_hi(u.w);
      }
      dot += (n == 0) ? b0 : b1;
      lg[n - n0c] = dot;
      lmax = fmaxf(lmax, dot);
    }
#pragma unroll
    for (int off = 32; off; off >>= 1) lmax = fmaxf(lmax, __shfl_down(lmax, off));
    if ((tid2 & 63) == 0) red[wv2] = lmax;
    __syncthreads();
    float M = fmaxf(fmaxf(red[0], red[1]), fmaxf(red[2], red[3]));
    float s = 0.f, acc[32] = {};
    for (int n = n0c + tid2; n < n1c; n += 256) {
      float p = ex2(lg[n - n0c] - M);
      s += p;
      const uint4* vr = (const uint4*)(vbh + (size_t)n * MDIM);
#pragma unroll
      for (int gg = 0; gg < 4; ++gg) {
        uint4 u = vr[gg];
        acc[8*gg+0] += p * bf_lo(u.x); acc[8*gg+1] += p * bf_hi(u.x);
        acc[8*gg+2] += p * bf_lo(u.y); acc[8*gg+3] += p * bf_hi(u.y);
        acc[8*gg+4] += p * bf_lo(u.z); acc[8*gg+5] += p * bf_hi(u.z);
        acc[8*gg+6] += p * bf_lo(u.w); acc[8*gg+7] += p * bf_hi(u.w);
      }
    }
#pragma unroll
    for (int off = 32; off; off >>= 1) {
      s += __shfl_down(s, off);
#pragma unroll
      for (int d = 0; d < 32; ++d) acc[d] += __shfl_down(acc[d], off);
    }
    if ((tid2 & 63) == 0) {
      sw[wv2] = s;
#pragma unroll
      for (int d = 0; d < 32; ++d) accw[wv2 * 32 + d] = acc[d];
    }
    __syncthreads();
    if (tid2 < 32) {
      float S = sw[0] + sw[1] + sw[2] + sw[3];
      float o = accw[tid2] + accw[32 + tid2] + accw[64 + tid2] + accw[96 + tid2];
      float* pp = gpart + ((size_t)bh * GCH + ch) * 36;
      if (tid2 == 0) { pp[0] = M; pp[1] = S; }
      pp[2 + tid2] = o;
    }
  }
}

// ---------------- K4: x1 projection (0..293) + parallel glob finalize (294..297) ----------------
__global__ __launch_bounds__(256, 4) void k_proj_mfma(
    const u16* __restrict__ x1b, const u16* __restrict__ wph,
    const float* __restrict__ bproj, float* __restrict__ out,
    const float* __restrict__ gpart, const float* __restrict__ wprojg,
    const float* __restrict__ bprojg)
{
  __shared__ __align__(16) u16 Ab[128][72];   // x1 rows (tokens)
  __shared__ __align__(16) u16 Bb[128][72];   // wproj rows (out cols)
  int tid = threadIdx.x;
  int id = blockIdx.x;
  if (id >= 294) {
    // glob finalize: one block per batch element
    int b = id - 294;
    float* x0s = (float*)&Ab[0][0];   // 384 floats
    for (int it = tid; it < NHEAD * 32; it += 256) {
      int h = it >> 5, d = it & 31;
      const float* pp = gpart + (size_t)(b * NHEAD + h) * GCH * 36;
      float M = -INFINITY;
#pragma unroll
      for (int c = 0; c < GCH; ++c) M = fmaxf(M, pp[c * 36]);
      float S = 0.f, o = 0.f;
#pragma unroll
      for (int c = 0; c < GCH; ++c) {
        float f = ex2(pp[c * 36] - M);
        S += pp[c * 36 + 1] * f;
        o += pp[c * 36 + 2 + d] * f;
      }
      x0s[h * 32 + d] = o / S;
    }
    __syncthreads();
    for (int c = tid; c < CDIM; c += 256) {
      float acc = bprojg[c];
      for (int kk = 0; kk < CDIM; ++kk) acc += x0s[kk] * wprojg[(size_t)kk * CDIM + c];
      out[(size_t)b * NTOK * CDIM + c] = acc;
    }
    return;
  }
  int lane = tid & 63, wv = tid >> 6;
  int r16 = lane & 15, g = lane >> 4;
  const int q8 = 36, r8 = 6;
  int xcd = id & 7, idx = id >> 3;
  int wgid = (xcd < r8 ? xcd * (q8 + 1) : r8 * (q8 + 1) + (xcd - r8) * q8) + idx;
  int by = wgid % 3, bx = wgid / 3;
  int row0 = bx * 128, n0 = by * 128;
  int wc = wv >> 1, wtk = wv & 1;
  int srow = tid >> 3, sseg = tid & 7;
  f32x4 acc[4][4] = {};                       // [col frag][row frag]
  for (int k0 = 0; k0 < CDIM; k0 += 64) {
    __syncthreads();
#pragma unroll
    for (int p = 0; p < 4; ++p) {
      int row = srow + p * 32;
      *(uint4*)&Ab[row][sseg * 8] = *(const uint4*)(x1b + (size_t)(row0 + row) * CDIM + k0 + sseg * 8);
      *(uint4*)&Bb[row][sseg * 8] = *(const uint4*)(wph + (size_t)(n0 + row) * CDIM + k0 + sseg * 8);
    }
    __syncthreads();
#pragma unroll
    for (int ks = 0; ks < 2; ++ks) {
      bf16x8 cf[4], rf[4];
#pragma unroll
      for (int i = 0; i < 4; ++i) {
        cf[i] = *(const bf16x8*)&Bb[wc * 64 + i * 16 + r16][ks * 32 + g * 8];
        rf[i] = *(const bf16x8*)&Ab[wtk * 64 + i * 16 + r16][ks * 32 + g * 8];
      }
#pragma unroll
      for (int i = 0; i < 4; ++i)
#pragma unroll
        for (int j = 0; j < 4; ++j)
          acc[i][j] = __builtin_amdgcn_mfma_f32_16x16x32_bf16(cf[i], rf[j], acc[i][j], 0, 0, 0);
    }
  }
#pragma unroll
  for (int i = 0; i < 4; ++i) {
    int col = n0 + wc * 64 + i * 16 + 4 * g;
    float4 bpv = *(const float4*)(bproj + col);
#pragma unroll
    for (int j = 0; j < 4; ++j) {
      int rr = row0 + wtk * 64 + j * 16 + r16;
      int b = (rr >= NPIX) + (rr >= 2 * NPIX) + (rr >= 3 * NPIX);
      int p = rr - b * NPIX;
      f32x4 v = acc[i][j];
      float4 o = make_float4(v.x + bpv.x, v.y + bpv.y, v.z + bpv.z, v.w + bpv.w);
      *(float4*)&out[((size_t)b * NTOK + 1 + p) * CDIM + col] = o;
    }
  }
}

extern "C" void kernel_launch(void* const* d_in, const int* in_sizes, int n_in,
                              void* d_out, int out_size, void* d_ws, size_t ws_size,
                              hipStream_t stream)
{
  const float* x      = (const float*)d_in[0];
  const float* wq     = (const float*)d_in[1];
  const float* wkv    = (const float*)d_in[2];
  const float* wproj  = (const float*)d_in[3];
  const float* bproj  = (const float*)d_in[4];
  const float* wqg    = (const float*)d_in[5];
  const float* wkvg   = (const float*)d_in[6];
  const float* wprojg = (const float*)d_in[7];
  const float* bprojg = (const float*)d_in[8];
  const float* lbt    = (const float*)d_in[9];
  const float* g2l    = (const float*)d_in[10];
  const float* g2g    = (const float*)d_in[11];
  const int*   rel    = (const int*)d_in[12];
  float* out = (float*)d_out;

  char* wsb = (char*)d_ws;
  const size_t hbsz = (size_t)BATCH * NHEAD * NTOKP * MDIM * 2;
  u16* qb  = (u16*)wsb;     wsb += hbsz;
  u16* kb  = (u16*)wsb;     wsb += hbsz;
  u16* vb  = (u16*)wsb;     wsb += hbsz;
  u16* kgb = (u16*)wsb;     wsb += hbsz;
  u16* vgb = (u16*)wsb;     wsb += hbsz;
  u16* x1b = (u16*)wsb;     wsb += (size_t)BATCH * NPIX * CDIM * 2;
  float* bias_pk = (float*)wsb; wsb += (size_t)NHEAD * 4 * NT * 64 * 4 * 4;
  u16* xb = (u16*)wsb;      wsb += (size_t)NROWP * CDIM * 2;
  u16* Wt = (u16*)wsb;      wsb += (size_t)1920 * CDIM * 2;
  u16* wph = (u16*)wsb;     wsb += (size_t)CDIM * CDIM * 2;
  int* ktokA = (int*)wsb;   wsb += (size_t)64 * NKEYP * 4;
  int* ktokL = (int*)wsb;   wsb += (size_t)64 * NKEYP * 4;
  float* qgw = (float*)wsb; wsb += (size_t)BATCH * CDIM * 4;
  float* gpart = (float*)wsb; wsb += (size_t)BATCH * NHEAD * GCH * 36 * 4;
  u32* tmask = (u32*)wsb;   wsb += (size_t)64 * 4;
  u16* msk16 = (u16*)wsb;   wsb += (size_t)64 * NT * 2;

  k_prep_all<<<3069, 256, 0, stream>>>(x, xb, wq, wkv, wkvg, Wt, wproj, wph,
                                       ktokA, ktokL, lbt, g2l, rel, bias_pk,
                                       wqg, qgw, tmask, msk16);

  k_qkv_mfma<<<1500, 256, 0, stream>>>(xb, Wt, qb, kb, vb, kgb, vgb);

  k_local<<<3456, 256, 0, stream>>>(qb, kb, vb, bias_pk, ktokA, ktokL, tmask, msk16,
                                    x1b, qgw, kgb, vgb, g2l, g2g, gpart);

  k_proj_mfma<<<298, 256, 0, stream>>>(x1b, wph, bproj, out,
                                       gpart, wprojg, bprojg);
}